// Round 5
// baseline (797.541 us; speedup 1.0000x reference)
//
#include <hip/hip_runtime.h>

// R20: depth-1 pipelined CG, 12-dot EXACT-BILINEAR reconstruction.
// History: R16-R18 (9-dot) failed big; R19 bisect PASSED (R15 algorithm on
// tagged-ring fp64 transport, absmax 0.154, 214us) => transport sound.
// Root cause of R16-R18 (consistent with all data): the 9-dot form used
// symmetry substitutions q.r=w.w and z'.r=s'.w, valid only if the recurrence
// invariants w=Ar, z'=As' hold EXACTLY. fp32 drift (~1e-5..1e-4 rel by k=50,
// growing as ||r|| shrinks) x trajectory amplification ~1.5e6 (calibrated
// from R19: 1e-7 coeff noise -> 0.154 absmax) = 15..1500 = observed 389-1170.
// Fix: post 12 dots (add q.r, z'.r, z'.w) -> reconstruction is pure bilinear
// algebra on the ACTUAL stored vectors; gam/del match R19's direct dots to
// ~1e-12 by construction. Prediction: absmax ~0.15, dispatch ~140-165us.

#define HH 1024
#define WW 1024
#define CG_STEPS 50
#define NB 256        // one block per CU; each block owns 4 grid rows
#define NT 1024       // one thread per column (16 waves)
#define RING 4        // reduction ring depth (safety proof: R17 notes + R19)
#define ND 12         // dots per iteration

#define SCOPE __HIP_MEMORY_SCOPE_AGENT

__device__ __forceinline__ float aload(const float* p) {
    return __hip_atomic_load(p, __ATOMIC_RELAXED, SCOPE);
}
__device__ __forceinline__ void astore(float* p, float v) {
    __hip_atomic_store(p, v, __ATOMIC_RELAXED, SCOPE);
}
__device__ __forceinline__ int iload(const int* p) {
    return __hip_atomic_load(p, __ATOMIC_RELAXED, SCOPE);
}
__device__ __forceinline__ void istore(int* p, int v) {
    __hip_atomic_store(p, v, __ATOMIC_RELAXED, SCOPE);
}
__device__ __forceinline__ unsigned long long uload(const unsigned long long* p) {
    return __hip_atomic_load(p, __ATOMIC_RELAXED, SCOPE);
}
__device__ __forceinline__ void ustore(unsigned long long* p, unsigned long long v) {
    __hip_atomic_store(p, v, __ATOMIC_RELAXED, SCOPE);
}

// tagged 48-bit double: [tag:16][bits(d)>>16:48]. tag <= 50; 0xAA-poison top16
// = 0xAAAA != any tag; stale tags != wanted tag. Truncation rel err 2^-36.
__device__ __forceinline__ unsigned long long packtd(unsigned tag, double d) {
    return ((unsigned long long)tag << 48) |
           (((unsigned long long)__double_as_longlong(d)) >> 16);
}
__device__ __forceinline__ double unpacktd(unsigned long long v) {
    return __longlong_as_double((long long)(v << 16));
}

// __launch_bounds__(1024, 4): 4 waves/SIMD min => VGPR capped at 128 so the
// 16-wave block stays launchable (spill >> launch-failure).
__global__ __launch_bounds__(NT, 4)
void cgsolve_kernel(const int* __restrict__ cols, const float* __restrict__ vals,
                    const float* __restrict__ b, float* __restrict__ xout,
                    float* __restrict__ rbuf,
                    unsigned long long* __restrict__ red0,
                    unsigned long long* __restrict__ redr,
                    int* __restrict__ flags) {
    const int col = threadIdx.x;
    const int bb  = blockIdx.x;

    __shared__ float  sr[4][WW + 1];
    __shared__ double sa[16][ND];      // post-side wave partials (fp64)
    __shared__ double sc[4][ND];       // consume-side per-wave partials (fp64)
    __shared__ int    scols[2][5 * WW];
    __shared__ float  svals[2][5 * WW];

    float adiag[4], art[4], alf[4], adn[4], awu[4];
    float x_[4], r_[4], w_[4], q_[4];
    float p_[4] = {0.f, 0.f, 0.f, 0.f};
    float s_[4] = {0.f, 0.f, 0.f, 0.f};
    float z_[4] = {0.f, 0.f, 0.f, 0.f};

    // ---- prologue: LDS-staged MATCHED COO parse (decode by col value — no
    // entry-order assumption; R7's positional variant failed on HW). Two rows
    // staged per round with int2/float2 vector loads (alignment proven R15).
    for (int half = 0; half < 2; ++half) {
        __syncthreads();                       // protect LDS reuse across rounds
        #pragma unroll
        for (int rr2 = 0; rr2 < 2; ++rr2) {
            const int i    = 4 * bb + 2 * half + rr2;
            const int off  = (i == 0) ? 0 : (4 * WW - 2) + (i - 1) * (5 * WW - 2);
            const int base = 1 + (i > 0) + (i < HH - 1);
            const int len2 = (base * WW + 2 * WW - 2) >> 1;   // int2 count
            const int2*   gc = (const int2*)(cols + off);
            const float2* gv = (const float2*)(vals + off);
            int2*   lc = (int2*)scols[rr2];
            float2* lv = (float2*)svals[rr2];
            for (int e = threadIdx.x; e < len2; e += NT) {
                lc[e] = gc[e];
                lv[e] = gv[e];
            }
        }
        __syncthreads();
        #pragma unroll
        for (int rr2 = 0; rr2 < 2; ++rr2) {
            const int rr     = 2 * half + rr2;
            const int i      = 4 * bb + rr;
            const int base   = 1 + (i > 0) + (i < HH - 1);
            const int j      = col;
            const int within = (j == 0) ? 0 : (base + 1) + (j - 1) * (base + 2);
            const int nnz    = base + (j > 0) + (j < WW - 1);
            const int t      = i * WW + j;
            float dg = 0.f, wr = 0.f, wl = 0.f, wd = 0.f, wu = 0.f;
            #pragma unroll
            for (int e = 0; e < 5; ++e) {
                if (e < nnz) {
                    const int   c = scols[rr2][within + e];
                    const float v = svals[rr2][within + e];
                    if (c == t)           dg = v;
                    else if (c == t + 1)  wr = v;
                    else if (c == t - 1)  wl = v;
                    else if (c == t + WW) wd = v;
                    else if (c == t - WW) wu = v;
                }
            }
            adiag[rr] = dg; art[rr] = wr; alf[rr] = wl; adn[rr] = wd; awu[rr] = wu;
            r_[rr] = b[t];
            x_[rr] = 0.f;
        }
    }

    // ---- setup: w0 = A r0 (halos straight from b); publish halo0; post
    // tag 0 = (gamma0, delta0) fp64 into red0 + flag 1 (R19-proven shape).
    {
        #pragma unroll
        for (int rr = 0; rr < 4; ++rr) sr[rr][col] = r_[rr];
        __syncthreads();
        const float btop = (bb > 0)      ? b[(4 * bb - 1) * WW + col] : 0.f;
        const float bbot = (bb < NB - 1) ? b[(4 * bb + 4) * WW + col] : 0.f;
        double rs_d = 0.0, dl_d = 0.0;
        #pragma unroll
        for (int rr = 0; rr < 4; ++rr) {
            float sum = adiag[rr] * r_[rr];
            const float vr = (col < WW - 1) ? sr[rr][col + 1] : 0.f;
            const float vl = (col > 0)      ? sr[rr][col - 1] : 0.f;
            sum += art[rr] * vr + alf[rr] * vl;
            const float vd = (rr < 3) ? r_[rr + 1] : bbot;
            const float vu = (rr > 0) ? r_[rr - 1] : btop;
            sum += adn[rr] * vd + awu[rr] * vu;
            w_[rr] = sum;
            rs_d += (double)r_[rr] * r_[rr];
            dl_d += (double)sum * r_[rr];
        }
        astore(&rbuf[(2 * bb + 0) * WW + col], w_[0]);   // halo 0, buffer 0
        astore(&rbuf[(2 * bb + 1) * WW + col], w_[3]);
        #pragma unroll
        for (int mask = 1; mask < 64; mask <<= 1) {
            rs_d += __shfl_xor(rs_d, mask, 64);
            dl_d += __shfl_xor(dl_d, mask, 64);
        }
        const int lane = threadIdx.x & 63, wid = threadIdx.x >> 6;
        if (lane == 0) { sa[wid][0] = rs_d; sa[wid][1] = dl_d; }
        __syncthreads();                       // drains halo stores < flag
        if (threadIdx.x < 16) {
            double t0 = sa[threadIdx.x][0], t1 = sa[threadIdx.x][1];
            #pragma unroll
            for (int mask = 1; mask < 16; mask <<= 1) {
                t0 += __shfl_xor(t0, mask, 16);
                t1 += __shfl_xor(t1, mask, 16);
            }
            if (threadIdx.x == 0) {
                ustore(red0 + bb,      packtd(0u, t0));
                ustore(red0 + NB + bb, packtd(0u, t1));
                istore(&flags[bb], 1);
            }
        }
    }

    double gamma_prev = 1.0, alpha_prev = 1.0, beta_prev = 0.0;

    #pragma unroll 1
    for (int k = 0; k < CG_STEPS; ++k) {
        if (k < CG_STEPS - 1) {
            // ---- phase A: stage w_k into LDS, poll neighbor halo flags, ONE
            // barrier, then read LDS + halos and compute q = A w.
            #pragma unroll
            for (int rr = 0; rr < 4; ++rr) sr[rr][col] = w_[rr];
            if (threadIdx.x < 2) {
                const int nb2 = bb + (threadIdx.x ? 1 : -1);
                if (nb2 >= 0 && nb2 < NB)
                    while (iload(&flags[nb2]) < k + 1) __builtin_amdgcn_s_sleep(1);
            }
            __syncthreads();                   // barrier1
            const float* hb = rbuf + (size_t)(k & 1) * 2 * NB * WW;
            const float wtop = (bb > 0)
                ? aload(&hb[(2 * (bb - 1) + 1) * WW + col]) : 0.f;
            const float wbot = (bb < NB - 1)
                ? aload(&hb[(2 * (bb + 1) + 0) * WW + col]) : 0.f;
            #pragma unroll
            for (int rr = 0; rr < 4; ++rr) {
                float sum = adiag[rr] * w_[rr];
                const float vr = (col < WW - 1) ? sr[rr][col + 1] : 0.f;
                const float vl = (col > 0)      ? sr[rr][col - 1] : 0.f;
                sum += art[rr] * vr + alf[rr] * vl;
                const float vd = (rr < 3) ? w_[rr + 1] : wbot;
                const float vu = (rr > 0) ? w_[rr - 1] : wtop;
                sum += adn[rr] * vd + awu[rr] * vu;
                q_[rr] = sum;
            }

            // ---- phase B: EARLY POST of tag k = 12 fp64 dots of PRE-update
            // vectors {r_k, w_k, q_k, s_{k-1}, z_{k-1}}. NO symmetry/invariant
            // substitutions (that was R16-R18's bug): q.r, z'.r, z'.w are
            // posted as their own dots. Ring/halo overwrite safety: the post
            // is data-dependent on ALL 1024 halo loads (q -> dots -> sa ->
            // barrierP -> thread-0 read), so consuming tag k proves every
            // block finished its iter-k halo reads.
            double d0 = 0., d1 = 0., d2 = 0., d3 = 0., d4 = 0., d5 = 0.,
                   d6 = 0., d7 = 0., d8 = 0., d9 = 0., d10 = 0., d11 = 0.;
            #pragma unroll
            for (int rr = 0; rr < 4; ++rr) {
                const double rd = r_[rr], wd = w_[rr], qd = q_[rr];
                const double sd = s_[rr], zd = z_[rr];
                d0  += rd * rd;   // r.r
                d1  += rd * wd;   // r.w
                d2  += wd * wd;   // w.w
                d3  += rd * sd;   // r.s'
                d4  += wd * sd;   // w.s'
                d5  += sd * sd;   // s'.s'
                d6  += qd * wd;   // q.w
                d7  += qd * sd;   // q.s'
                d8  += zd * sd;   // z'.s'
                d9  += qd * rd;   // q.r   (NOT substituted by w.w)
                d10 += zd * rd;   // z'.r  (NOT substituted by w.s')
                d11 += zd * wd;   // z'.w  (NOT substituted by q.s')
            }
            double d[ND] = {d0, d1, d2, d3, d4, d5, d6, d7, d8, d9, d10, d11};
            #pragma unroll
            for (int mask = 1; mask < 64; mask <<= 1) {
                #pragma unroll
                for (int j = 0; j < ND; ++j) d[j] += __shfl_xor(d[j], mask, 64);
            }
            {
                const int lane = threadIdx.x & 63, wid = threadIdx.x >> 6;
                if (lane == 0) {
                    #pragma unroll
                    for (int j = 0; j < ND; ++j) sa[wid][j] = d[j];
                }
            }
            __syncthreads();               // barrierP
            if (threadIdx.x < 16) {
                double t[ND];
                #pragma unroll
                for (int j = 0; j < ND; ++j) t[j] = sa[threadIdx.x][j];
                #pragma unroll
                for (int mask = 1; mask < 16; mask <<= 1) {
                    #pragma unroll
                    for (int j = 0; j < ND; ++j) t[j] += __shfl_xor(t[j], mask, 16);
                }
                if (threadIdx.x == 0) {
                    unsigned long long* bp =
                        redr + (size_t)(k & (RING - 1)) * ND * NB + bb;
                    #pragma unroll
                    for (int j = 0; j < ND; ++j)
                        ustore(bp + j * NB, packtd((unsigned)k, t[j]));
                }
            }
        }

        // ---- phase C consume: k=0 reads red0 (true gamma0/delta0); k>=1
        // reads tag k-1 (posted a full iteration ago -> near-zero poll) and
        // reconstructs gamma_k/delta_k by EXACT bilinear assembly.
        double gam, del;
        if (k == 0) {
            if (threadIdx.x < NB) {
                unsigned long long v0 = uload(red0 + threadIdx.x);
                unsigned long long v1 = uload(red0 + NB + threadIdx.x);
                while ((v0 >> 48) != 0ull || (v1 >> 48) != 0ull) {
                    __builtin_amdgcn_s_sleep(1);
                    if ((v0 >> 48) != 0ull) v0 = uload(red0 + threadIdx.x);
                    if ((v1 >> 48) != 0ull) v1 = uload(red0 + NB + threadIdx.x);
                }
                double t0 = unpacktd(v0), t1 = unpacktd(v1);
                #pragma unroll
                for (int mask = 1; mask < 64; mask <<= 1) {
                    t0 += __shfl_xor(t0, mask, 64);
                    t1 += __shfl_xor(t1, mask, 64);
                }
                if ((threadIdx.x & 63) == 0) {
                    const int g = threadIdx.x >> 6;
                    sc[g][0] = t0; sc[g][1] = t1;
                }
            }
            __syncthreads();               // barrierC
            gam = ((sc[0][0] + sc[1][0]) + sc[2][0]) + sc[3][0];
            del = ((sc[0][1] + sc[1][1]) + sc[2][1]) + sc[3][1];
        } else {
            if (threadIdx.x < NB) {        // waves 0..3: one source block/thread
                const unsigned want = (unsigned)(k - 1);
                const unsigned long long* bp =
                    redr + (size_t)((k - 1) & (RING - 1)) * ND * NB + threadIdx.x;
                unsigned long long v[ND];
                #pragma unroll
                for (int j = 0; j < ND; ++j) v[j] = uload(bp + j * NB);
                for (;;) {
                    bool ok = true;
                    #pragma unroll
                    for (int j = 0; j < ND; ++j)
                        ok &= ((unsigned)(v[j] >> 48) == want);
                    if (ok) break;
                    __builtin_amdgcn_s_sleep(1);
                    #pragma unroll
                    for (int j = 0; j < ND; ++j)
                        if ((unsigned)(v[j] >> 48) != want)
                            v[j] = uload(bp + j * NB);
                }
                double t[ND];
                #pragma unroll
                for (int j = 0; j < ND; ++j) t[j] = unpacktd(v[j]);
                #pragma unroll
                for (int mask = 1; mask < 64; mask <<= 1) {
                    #pragma unroll
                    for (int j = 0; j < ND; ++j) t[j] += __shfl_xor(t[j], mask, 64);
                }
                if ((threadIdx.x & 63) == 0) {
                    const int g = threadIdx.x >> 6;
                    #pragma unroll
                    for (int j = 0; j < ND; ++j) sc[g][j] = t[j];
                }
            }
            __syncthreads();               // barrierC
            double S[ND];
            #pragma unroll
            for (int j = 0; j < ND; ++j)
                S[j] = ((sc[0][j] + sc[1][j]) + sc[2][j]) + sc[3][j];
            // S: 0 r.r | 1 r.w | 2 w.w | 3 r.s' | 4 w.s' | 5 s'.s' |
            //    6 q.w | 7 q.s' | 8 z'.s' | 9 q.r | 10 z'.r | 11 z'.w
            const double a  = alpha_prev, bt = beta_prev;
            const double rsk = S[1] + bt * S[3];                       // r.s_k
            const double ssk = S[2] + 2.0 * bt * S[4] + bt * bt * S[5];// s.s
            const double wsk = S[2] + bt * S[4];                       // w.s_k
            const double zrk = S[9] + bt * S[10];                      // z_k.r
            const double zsk = S[6] + bt * (S[7] + S[11]) + bt * bt * S[8];
            gam = S[0] - 2.0 * a * rsk + a * a * ssk;   // r_k.r_k
            del = S[1] - a * (wsk + zrk) + a * a * zsk; // w_k.r_k
        }

        const double beta  = (k == 0) ? 0.0 : gam / gamma_prev;
        const double alpha = (k == 0) ? gam / del
                                      : gam / (del - beta * gam / alpha_prev);
        const float betaf = (float)beta, alphaf = (float)alpha;
        #pragma unroll
        for (int rr = 0; rr < 4; ++rr) {
            p_[rr] = r_[rr] + betaf * p_[rr];
            x_[rr] += alphaf * p_[rr];
        }
        if (k == CG_STEPS - 1) break;

        // ---- phase D: vector updates (pre-update values were already posted)
        #pragma unroll
        for (int rr = 0; rr < 4; ++rr) {
            z_[rr] = q_[rr] + betaf * z_[rr];
            s_[rr] = w_[rr] + betaf * s_[rr];
            r_[rr] -= alphaf * s_[rr];
            w_[rr] -= alphaf * z_[rr];
        }
        // ---- phase E: publish w-halo k+1 (double-buffered). Overwrite-safe:
        // we consumed tag k-1, so every block posted tag k-1, which is
        // data-dependent on its iter-(k-1) halo reads of this parity.
        float* hbn = rbuf + (size_t)((k + 1) & 1) * 2 * NB * WW;
        astore(&hbn[(2 * bb + 0) * WW + col], w_[0]);
        astore(&hbn[(2 * bb + 1) * WW + col], w_[3]);
        __syncthreads();                   // barrierH: drain halo stores < flag
        if (threadIdx.x == 0) istore(&flags[bb], k + 2);

        gamma_prev = gam; alpha_prev = alpha; beta_prev = beta;
    }

    #pragma unroll
    for (int rr = 0; rr < 4; ++rr)
        xout[(4 * bb + rr) * WW + col] = x_[rr];
}

extern "C" void kernel_launch(void* const* d_in, const int* in_sizes, int n_in,
                              void* d_out, int out_size, void* d_ws, size_t ws_size,
                              hipStream_t stream) {
    const int*   cols = (const int*)d_in[1];
    const float* vals = (const float*)d_in[2];
    const float* b    = (const float*)d_in[3];
    float* x = (float*)d_out;

    // workspace layout — 4,297,728 B total, EXACTLY the R15-proven footprint:
    //   rbuf : 2 bufs * 2*NB rows * WW f32            = 4,194,304 B
    //   red0 : 2 * NB u64 (setup gamma0/delta0)       =     4,096 B
    //   redr : RING * ND * NB u64 (tagged fp64 ring)  =    98,304 B
    //   flags: NB int                                 =     1,024 B
    float* rbuf = (float*)d_ws;
    unsigned long long* red0 =
        (unsigned long long*)(rbuf + 2 * 2 * (size_t)NB * WW);
    unsigned long long* redr = red0 + 2 * NB;
    int* flags = (int*)(redr + (size_t)RING * ND * NB);

    // no memset: 0xAA poison fails every tag check (top16 = 0xAAAA != any
    // tag <= 50) and flags poison is negative (< any k+1).
    //
    // Regular launch: 256 blocks on 256 CUs, 16 waves/CU, ~100 KB LDS (<160)
    // -> 1 block/CU, all blocks resident by capacity (PROVEN R9/R10/R14).
    // Known-bad: R11 NT=1088 (illegal), R12 512-block (deadlock), R13
    // pre-issued polls (nondeterminism), R7 positional parse (wrong on HW),
    // R16-R18 9-dot reconstruction (invariant-drift amplification — see top).
    cgsolve_kernel<<<dim3(NB), dim3(NT), 0, stream>>>(cols, vals, b, x,
                                                      rbuf, red0, redr, flags);
}